// Round 11
// baseline (780.326 us; speedup 1.0000x reference)
//
#include <hip/hip_runtime.h>

typedef float f2 __attribute__((ext_vector_type(2)));
typedef float f4 __attribute__((ext_vector_type(4)));

#define TT 2048
#define BB 512
#define II 10
#define HH 20
#define CH 16                 // consumer steps per barrier / history depth
#define RS 32                 // ring slots = 2 chunks (double buffer)
#define NCHUNK (TT / CH)      // 128

#define LOG2E 1.44269504088896340736f

__device__ __forceinline__ float fexp2(float x) {
#if __has_builtin(__builtin_amdgcn_exp2f)
    return __builtin_amdgcn_exp2f(x);
#else
    return exp2f(x);
#endif
}

// One block = 2 waves per SAMPLE (s = blockIdx.x).
// Wave 0 (consumer): SKEWED DUAL SCAN. Lanes 0..19 hold BOTH directions'
//   state for hidden unit j as two register sets (A = forward, B = reverse).
//   The instruction stream alternates: read hb_B -> compute A (covers B's
//   LDS read latency) -> write h_A -> read hb_A -> compute B (covers A's
//   read latency) -> write h_B. Each scan's LDS round trip hides under the
//   other scan's ~150cy compute phase; DS pipe is in-order per wave, so
//   counted lgkmcnt waits keep both chains' reads in flight independently.
// Wave 1 (producer): xproj[t] = b + W_ih x[t] for both dirs (lanes 0..19 fwd,
//   32..51 rev) into a 32-slot LDS ring, double-buffered, 1 barrier/16 steps.
// Chunk-end: staged 2x16x20 h block dumped to HBM by all 64 lanes (10 each),
// store vmcnt drain off the recurrence.
// Gate rows pre-scaled by -log2e (-2log2e for g) so sigma/tanh use v_exp_f32
// (2^x) directly; tanh via 2*sigma-1 in FMA form.
__global__ __launch_bounds__(128, 1) void lstm_bidir(
    const float* __restrict__ x,
    const float* __restrict__ w_ih_f, const float* __restrict__ w_hh_f,
    const float* __restrict__ b_ih_f, const float* __restrict__ b_hh_f,
    const float* __restrict__ w_ih_r, const float* __restrict__ w_hh_r,
    const float* __restrict__ b_ih_r, const float* __restrict__ b_hh_r,
    float* __restrict__ out)
{
    const int tid  = threadIdx.x;
    const int wid  = tid >> 6;     // 0 = consumer, 1 = producer
    const int lane = tid & 63;
    const int s    = blockIdx.x;   // batch sample

    const bool valid = ((lane & 31) < HH);
    const int  j     = valid ? (lane & 31) : (HH - 1);   // clamp keeps loads in-bounds

    // Row scale per gate (i,f,g,o): sigmoid rows -log2e, tanh row -2log2e.
    const float gsc[4] = { -LOG2E, -LOG2E, -2.0f * LOG2E, -LOG2E };

    __shared__ f4    ring[RS][64];         // xproj ring: [slot][producer lane]
    __shared__ float hstage[2 * CH * 64];  // h history: [dir][step-in-chunk][lane]

    if (wid == 1) {
        // ---------------- producer wave (both halves, as R10) ----------------
        const int dirh = lane >> 5;            // 0 = fwd, 1 = rev
        const float* __restrict__ w_ih = dirh ? w_ih_r : w_ih_f;
        const float* __restrict__ b_ih = dirh ? b_ih_r : b_ih_f;
        const float* __restrict__ b_hh = dirh ? b_hh_r : b_hh_f;
        const int t0    = dirh ? (TT - 1) : 0;
        const int xstep = dirh ? -(BB * II) : (BB * II);
        const int xbase = (t0 * BB + s) * II;

        f2 wih[4][5];
        float bs[4];
#pragma unroll
        for (int g = 0; g < 4; ++g) {
            const int r = g * HH + j;
#pragma unroll
            for (int k = 0; k < 5; ++k) {
                f2 w = *(const f2*)(w_ih + r * II + 2 * k);
                wih[g][k] = w * gsc[g];
            }
            bs[g] = (b_ih[r] + b_hh[r]) * gsc[g];
        }

        auto produce8 = [&](int base) {
            f2 xb[8][5];
#pragma unroll
            for (int i = 0; i < 8; ++i) {
                int u = base + i; if (u > TT - 1) u = TT - 1;   // in-bounds clamp
                const float* px = x + (xbase + u * xstep);
#pragma unroll
                for (int k = 0; k < 5; ++k) xb[i][k] = *(const f2*)(px + 2 * k);
            }
#pragma unroll
            for (int i = 0; i < 8; ++i) {
                const int u = base + i;
                if (u < TT) {
                    f4 xp;
#pragma unroll
                    for (int g = 0; g < 4; ++g) {
                        f2 p = {bs[g], 0.f};
#pragma unroll
                        for (int k = 0; k < 5; ++k) p += wih[g][k] * xb[i][k];
                        xp[g] = p[0] + p[1];
                    }
                    ring[u & (RS - 1)][lane] = xp;
                }
            }
        };

        produce8(0);              // prefill steps 0..15
        produce8(8);
        for (int chunk = 0; chunk < NCHUNK; ++chunk) {
            __syncthreads();
            const int base = (chunk + 1) * CH;   // fill next chunk's half
            produce8(base);
            produce8(base + 8);
        }
    } else {
        // ------------- consumer wave: skewed dual scan (A=fwd, B=rev) -------------
        __builtin_amdgcn_s_setprio(1);

        f2 whhA[4][10], whhB[4][10];
#pragma unroll
        for (int g = 0; g < 4; ++g) {
            const int r = g * HH + j;
#pragma unroll
            for (int k = 0; k < 10; ++k) {
                f2 wA = *(const f2*)(w_hh_f + r * HH + 2 * k);
                f2 wB = *(const f2*)(w_hh_r + r * HH + 2 * k);
                whhA[g][k] = wA * gsc[g];
                whhB[g][k] = wB * gsc[g];
            }
        }

        const int ostepF = BB * 2 * HH;
        const int ostepR = -ostepF;
        const int obaseF = s * 2 * HH;                              // fwd t=0 base
        const int obaseR = ((TT - 1) * BB + s) * 2 * HH + HH;       // rev t=0 base

        // One full scan-step of one direction (pure register dataflow + xp seed).
        auto comp = [&](const f2 (&whh)[4][10], const f4 (&hb)[5], const f4& xp,
                        float& c, float& h) {
            f2 a0[4], a1[4];
#pragma unroll
            for (int g = 0; g < 4; ++g) { a0[g] = f2{xp[g], 0.f}; a1[g] = f2{0.f, 0.f}; }
#pragma unroll
            for (int k = 0; k < 5; ++k) {
                const f4 hv = hb[k];
                f2 lo; lo[0] = hv[0]; lo[1] = hv[1];
                f2 hi; hi[0] = hv[2]; hi[1] = hv[3];
#pragma unroll
                for (int g = 0; g < 4; ++g) {
                    a0[g] += whh[g][2 * k]     * lo;
                    a1[g] += whh[g][2 * k + 1] * hi;
                }
            }
            float u[4];
#pragma unroll
            for (int g = 0; g < 4; ++g) {
                const f2 a = a0[g] + a1[g];
                u[g] = a[0] + a[1];               // xp already seeded, exp2-ready
            }
            const float ig = __builtin_amdgcn_rcpf(1.0f + fexp2(u[0]));
            const float fg = __builtin_amdgcn_rcpf(1.0f + fexp2(u[1]));
            const float sg = __builtin_amdgcn_rcpf(1.0f + fexp2(u[2]));  // sigma(2 v_g)
            const float og = __builtin_amdgcn_rcpf(1.0f + fexp2(u[3]));
            const float i2 = ig + ig;
            const float o2 = og + og;
            const float m  = __builtin_fmaf(i2, sg, -ig);       // i * tanh(v_g)
            c = __builtin_fmaf(fg, c, m);
            const float sc_ = __builtin_amdgcn_rcpf(
                                1.0f + fexp2(c * (-2.0f * LOG2E)));  // sigma(2c)
            h = __builtin_fmaf(o2, sc_, -og);                   // o * tanh(c)
        };

        // Prime: B's first broadcast read (row 15 of B region) must be zeros.
        hstage[CH * 64 + (CH - 1) * 64 + lane] = 0.0f;

        f4 hbA[5], hbB[5];
#pragma unroll
        for (int k = 0; k < 5; ++k) hbA[k] = f4{0.f, 0.f, 0.f, 0.f};

        float cA = 0.f, hA = 0.f, cB = 0.f, hB = 0.f;
        int t = 0;

        for (int chunk = 0; chunk < NCHUNK; ++chunk) {
            __syncthreads();
            f4 xpA = ring[t & (RS - 1)][j];
            f4 xpB = ring[t & (RS - 1)][32 + j];
#pragma unroll
            for (int i = 0; i < CH; ++i, ++t) {
                // phase 1: read h_B(t-1) (written end of prev iter; latency
                // hidden under phase 2)
#pragma unroll
                for (int k = 0; k < 5; ++k)
                    hbB[k] = *(const f4*)&hstage[CH * 64 + (((i + CH - 1) & (CH - 1)) * 64) + 4 * k];

                // phase 2: compute A step t (hbA ready from prev iter)
                comp(whhA, hbA, xpA, cA, hA);

                // phase 3: stage h_A
                hstage[i * 64 + lane] = hA;
                __builtin_amdgcn_wave_barrier();

                // phase 4: read h_A(t) for next iter (latency hidden under phase 5)
#pragma unroll
                for (int k = 0; k < 5; ++k)
                    hbA[k] = *(const f4*)&hstage[i * 64 + 4 * k];

                // phase 5: compute B step t
                comp(whhB, hbB, xpB, cB, hB);

                // phase 6: stage h_B
                hstage[CH * 64 + i * 64 + lane] = hB;
                __builtin_amdgcn_wave_barrier();

                // phase 7: ring reads for t+1 (a full iteration of slack)
                if (i < CH - 1) {
                    xpA = ring[(t + 1) & (RS - 1)][j];
                    xpB = ring[(t + 1) & (RS - 1)][32 + j];
                }
            }

            // ---- dump the chunk's 2x16x20 h block to HBM (off the chain) ----
#pragma unroll
            for (int q = 0; q < 10; ++q) {
                const int sc  = q / 5;               // 0 = A/fwd, 1 = B/rev
                const int idx = (q % 5) * 64 + lane; // 0..319 within direction
                const int td  = idx / HH;
                const int jd  = idx - td * HH;
                const float v = hstage[sc * CH * 64 + td * 64 + jd];
                const int tglob = chunk * CH + td;
                const int o = sc ? (obaseR + tglob * ostepR + jd)
                                 : (obaseF + tglob * ostepF + jd);
                out[o] = v;
            }
        }
    }
}

extern "C" void kernel_launch(void* const* d_in, const int* in_sizes, int n_in,
                              void* d_out, int out_size, void* d_ws, size_t ws_size,
                              hipStream_t stream) {
    const float* xp     = (const float*)d_in[0];
    const float* w_ih_f = (const float*)d_in[1];
    const float* w_hh_f = (const float*)d_in[2];
    const float* b_ih_f = (const float*)d_in[3];
    const float* b_hh_f = (const float*)d_in[4];
    const float* w_ih_r = (const float*)d_in[5];
    const float* w_hh_r = (const float*)d_in[6];
    const float* b_ih_r = (const float*)d_in[7];
    const float* b_hh_r = (const float*)d_in[8];
    float* outp = (float*)d_out;

    hipLaunchKernelGGL(lstm_bidir, dim3(512), dim3(128), 0, stream,
                       xp, w_ih_f, w_hh_f, b_ih_f, b_hh_f,
                       w_ih_r, w_hh_r, b_ih_r, b_hh_r, outp);
}